// Round 15
// baseline (147.824 us; speedup 1.0000x reference)
//
#include <hip/hip_runtime.h>
#include <math.h>

typedef unsigned short u16;
typedef unsigned long long u64;
typedef __attribute__((ext_vector_type(8))) short bf16x8;
typedef __attribute__((ext_vector_type(4))) float f32x4;

__device__ __forceinline__ float sigf(float x)  { return 1.0f / (1.0f + __expf(-x)); }
__device__ __forceinline__ float tanhf_(float x){ float e = __expf(2.0f * x); return 1.0f - 2.0f / (e + 1.0f); }
__device__ __forceinline__ u16 f2bf(float f) {
    unsigned x = __float_as_uint(f);
    return (u16)((x + 0x7fffu + ((x >> 16) & 1u)) >> 16);
}

// u64-key sorted insert: keys k0<=k1<=k2<=k3, key = (asuint(d2)<<24)|idx.
// d2 >= 0 so asuint is order-isomorphic; sqrt is monotone, so (d2,idx) order ==
// np's (dist,idx) order (verified bit-identical on this dataset in r14).
#define INSU(KEY) do {                                                              \
    u64 _k = (KEY);                                                                 \
    k3 = (_k < k3) ? _k : k3;                                                       \
    { bool _c = k3 < k2; u64 _lo = _c ? k3 : k2, _hi = _c ? k2 : k3; k2 = _lo; k3 = _hi; } \
    { bool _c = k2 < k1; u64 _lo = _c ? k2 : k1, _hi = _c ? k1 : k2; k1 = _lo; k2 = _hi; } \
    { bool _c = k1 < k0; u64 _lo = _c ? k1 : k0, _hi = _c ? k0 : k1; k0 = _lo; k1 = _hi; } \
} while (0)

// float-key variant for the fallback kernel (round-5 proven path)
#define INS4(D, J) do {                                                              \
    float _d = (D); int _j = (J);                                                    \
    if (_d < bd3 || (_d == bd3 && _j < bj3)) {                                       \
        bd3 = _d; bj3 = _j;                                                          \
        if (bd3 < bd2 || (bd3 == bd2 && bj3 < bj2)) {                                \
            float _t = bd2; bd2 = bd3; bd3 = _t; int _u = bj2; bj2 = bj3; bj3 = _u; }\
        if (bd2 < bd1 || (bd2 == bd1 && bj2 < bj1)) {                                \
            float _t = bd1; bd1 = bd2; bd2 = _t; int _u = bj1; bj1 = bj2; bj2 = _u; }\
        if (bd1 < bd0 || (bd1 == bd0 && bj1 < bj0)) {                                \
            float _t = bd0; bd0 = bd1; bd1 = _t; int _u = bj0; bj0 = bj1; bj1 = _u; }\
    } } while (0)

__global__ void diag_kernel(float* out, int code, int out_size) {
    if (out_size > 0) out[0] = (float)code * 1.0e8f;
}

// K1: blocks [0, knn_blocks): kNN top-4 + Linear(4,8)+ReLU emb -> out (fp32 [n,32]).
//     One WAVE per pedestrian; u64 packed d2-keys; shfl-xor butterfly merge.
//     blocks [knn_blocks, ...): bf16 weight prep into MFMA B-fragment order.
//     (byte-identical to round 14)
__global__ __launch_bounds__(256) void knn_prep_kernel(
    const float* __restrict__ obs1, const float* __restrict__ obs2,
    const float* __restrict__ Wemb, const float* __restrict__ bemb,
    const float* __restrict__ Wih,  const float* __restrict__ Whh,
    const float* __restrict__ Wp,
    u16* __restrict__ Wgf, u16* __restrict__ Wpf,
    int n, int knn_blocks, float* __restrict__ out)
{
    const int t = threadIdx.x;

    if (blockIdx.x >= knn_blocks) {
        int id = (blockIdx.x - knn_blocks) * 256 + t;
        if (id < 36864) {                        // gates: 64 gt * 9 kt * 64 lanes
            int gt = id / 576, rem = id - gt * 576;
            int kt = rem >> 6, ln = rem & 63;
            int g  = gt * 16 + (ln & 15);
            int k  = kt * 32 + (ln >> 4) * 8;
            u16* dst = Wgf + (size_t)id * 8;
            #pragma unroll
            for (int j = 0; j < 8; j++) {
                int kk = k + j;
                float v = (kk < 32) ? Wih[(size_t)g * 32 + kk]
                                    : Whh[(size_t)g * 256 + (kk - 32)];
                dst[j] = f2bf(v);
            }
        } else if (id < 37888) {                 // pool: 2 pt * 8 kt * 64 lanes
            int id2 = id - 36864;
            int pt = id2 >> 9, rem = id2 & 511;
            int kt = rem >> 6, ln = rem & 63;
            int o  = pt * 16 + (ln & 15);
            int k  = kt * 32 + (ln >> 4) * 8;
            u16* dst = Wpf + (size_t)id2 * 8;
            #pragma unroll
            for (int j = 0; j < 8; j++)
                dst[j] = f2bf(Wp[(size_t)o * 256 + k + j]);
        }
        return;
    }

    const int lane = t & 63;
    const int wv   = t >> 6;
    const int i    = blockIdx.x * 4 + wv;
    if (i >= n) return;

    const float2* o2 = (const float2*)obs2;
    const float2 pi = o2[i];

    u64 k0 = ~0ull, k1 = ~0ull, k2 = ~0ull, k3 = ~0ull;

    int j = lane;
    for (; j + 192 < n; j += 256) {              // 4 coalesced 512B wave-loads in flight
        float2 p0 = o2[j], p1 = o2[j + 64], p2 = o2[j + 128], p3 = o2[j + 192];
        float dx, dy, d2; u64 key;
        dx = p0.x - pi.x; dy = p0.y - pi.y;
        d2 = __fadd_rn(__fmul_rn(dx, dx), __fmul_rn(dy, dy));
        key = (((u64)__float_as_uint(d2)) << 24) | (unsigned)j;
        key = (j == i) ? ~0ull : key;                         INSU(key);
        dx = p1.x - pi.x; dy = p1.y - pi.y;
        d2 = __fadd_rn(__fmul_rn(dx, dx), __fmul_rn(dy, dy));
        key = (((u64)__float_as_uint(d2)) << 24) | (unsigned)(j + 64);
        key = (j + 64 == i) ? ~0ull : key;                    INSU(key);
        dx = p2.x - pi.x; dy = p2.y - pi.y;
        d2 = __fadd_rn(__fmul_rn(dx, dx), __fmul_rn(dy, dy));
        key = (((u64)__float_as_uint(d2)) << 24) | (unsigned)(j + 128);
        key = (j + 128 == i) ? ~0ull : key;                   INSU(key);
        dx = p3.x - pi.x; dy = p3.y - pi.y;
        d2 = __fadd_rn(__fmul_rn(dx, dx), __fmul_rn(dy, dy));
        key = (((u64)__float_as_uint(d2)) << 24) | (unsigned)(j + 192);
        key = (j + 192 == i) ? ~0ull : key;                   INSU(key);
    }
    for (; j < n; j += 64) {
        float2 pj = o2[j];
        float dx = pj.x - pi.x, dy = pj.y - pi.y;
        float d2 = __fadd_rn(__fmul_rn(dx, dx), __fmul_rn(dy, dy));
        u64 key = (((u64)__float_as_uint(d2)) << 24) | (unsigned)j;
        key = (j == i) ? ~0ull : key;
        INSU(key);
    }

    #pragma unroll
    for (int m = 1; m < 64; m <<= 1) {
        u64 o0 = __shfl_xor(k0, m), o1 = __shfl_xor(k1, m);
        u64 o2_ = __shfl_xor(k2, m), o3 = __shfl_xor(k3, m);
        INSU(o0); INSU(o1); INSU(o2_); INSU(o3);
    }

    if (lane < 4) {
        u64 kq = (lane == 0) ? k0 : (lane == 1) ? k1 : (lane == 2) ? k2 : k3;
        int jn = (int)(kq & 0xFFFFFF);
        if (jn < 0 || jn >= n) jn = 0;
        float pix = pi.x, piy = pi.y;
        float pjx = obs2[2 * jn], pjy = obs2[2 * jn + 1];
        float px = pjx - pix, py = pjy - piy;
        float vix = pix - obs1[2 * i];
        float viy = piy - obs1[2 * i + 1];
        float vx = (pjx - obs1[2 * jn])     - vix;
        float vy = (pjy - obs1[2 * jn + 1]) - viy;
        float* dst = out + (size_t)i * 32 + lane * 8;
        #pragma unroll
        for (int e = 0; e < 8; e++) {
            float a = px * Wemb[e]      + py * Wemb[8 + e]
                    + vx * Wemb[16 + e] + vy * Wemb[24 + e]
                    + bemb[e];
            dst[e] = fmaxf(a, 0.0f);
        }
    }
}

// K2: 1024 threads = 16 waves, 16-row tile. Wave wv owns unit-tile ut = wv
// (hidden units [wv*16, wv*16+16)). Per wave: 4 gate-type MFMA accumulations
// (36 MFMA + 36 coalesced 1KB B-frag loads) -> LSTM pointwise in-lane -> sHb
// -> pool MFMA (waves 0,1). 16 waves/block doubles latency hiding vs r14.
// LDS 17,920 B.
__global__ __launch_bounds__(1024) void lstm_kernel(
    const float* __restrict__ h,   const float* __restrict__ c,
    const u16*  __restrict__ Wgf,  const float* __restrict__ bih,
    const float* __restrict__ bhh,
    const u16*  __restrict__ Wpf,  const float* __restrict__ bp,
    int n, float* __restrict__ out)
{
    __shared__ __align__(16) char lds[17920];
    u16* sXb = (u16*)lds;                     // [16][296] bf16 X=[emb|h]
    u16* sHb = (u16*)(lds + 9472);            // [16][264] bf16 h_new

    const int t    = threadIdx.x;             // 0..1023
    const int i0   = blockIdx.x * 16;
    const int lane = t & 63;
    const int wv   = t >> 6;                  // wave 0..15
    const int fm   = lane & 15;
    const int fq   = lane >> 4;

    // stage emb (fp32 in out) -> sXb[:,0:32): 512 floats, threads 0..511
    if (t < 512) {
        int r = t >> 5, e = t & 31;
        int row = i0 + r;
        float v = (row < n) ? out[(size_t)row * 32 + e] : 0.0f;
        sXb[r * 296 + e] = f2bf(v);
    }
    // stage h -> sXb[:,32:288): 1024 float4, one per thread
    {
        int r = t >> 6, k4 = t & 63;
        int row = i0 + r;
        float4 hv = (row < n) ? ((const float4*)h)[(size_t)row * 64 + k4]
                              : make_float4(0.f, 0.f, 0.f, 0.f);
        u16* d = &sXb[r * 296 + 32 + k4 * 4];
        d[0] = f2bf(hv.x); d[1] = f2bf(hv.y); d[2] = f2bf(hv.z); d[3] = f2bf(hv.w);
    }
    __syncthreads();

    // A-frags: lane holds X[row=fm][kt*32 + fq*8 + j]
    bf16x8 afr[9];
    #pragma unroll
    for (int kt = 0; kt < 9; kt++)
        afr[kt] = *(const bf16x8*)&sXb[fm * 296 + kt * 32 + fq * 8];

    // gates + pointwise: wave wv = unit tile ut, lane fm = hidden unit
    {
        const int ut = wv;                    // unit tile 0..15
        const int u  = ut * 16 + fm;          // hidden unit this lane owns

        f32x4 acc[4];
        #pragma unroll
        for (int jg = 0; jg < 4; jg++) acc[jg] = (f32x4){0.f, 0.f, 0.f, 0.f};

        #pragma unroll
        for (int jg = 0; jg < 4; jg++) {      // gate type i,f,g,o
            const int gt = jg * 16 + ut;
            const u16* wbase = Wgf + ((size_t)gt * 9) * 512 + lane * 8;
            #pragma unroll
            for (int kt = 0; kt < 9; kt++) {
                bf16x8 bfr = *(const bf16x8*)(wbase + kt * 512);  // coalesced 1 KB
                acc[jg] = __builtin_amdgcn_mfma_f32_16x16x32_bf16(afr[kt], bfr, acc[jg], 0, 0, 0);
            }
        }

        float b0 = bih[u]       + bhh[u];
        float b1 = bih[u + 256] + bhh[u + 256];
        float b2 = bih[u + 512] + bhh[u + 512];
        float b3 = bih[u + 768] + bhh[u + 768];

        #pragma unroll
        for (int r_ = 0; r_ < 4; r_++) {      // D-layout: row = fq*4 + r_
            int row = i0 + fq * 4 + r_;
            float cin = (row < n) ? c[(size_t)row * 256 + u] : 0.0f;
            float gi = acc[0][r_] + b0;
            float gf = acc[1][r_] + b1;
            float gg = acc[2][r_] + b2;
            float go = acc[3][r_] + b3;
            float cn = sigf(gf) * cin + sigf(gi) * tanhf_(gg);
            float hn = sigf(go) * tanhf_(cn);
            sHb[(fq * 4 + r_) * 264 + u] = f2bf(hn);
        }
    }
    __syncthreads();

    // pool GEMM via MFMA: M=16 x N=32 x K=256; waves 0,1 take one n-tile each
    if (wv < 2) {
        bf16x8 ah[8];
        #pragma unroll
        for (int kt = 0; kt < 8; kt++)
            ah[kt] = *(const bf16x8*)&sHb[fm * 264 + kt * 32 + fq * 8];
        const u16* wbase = Wpf + ((size_t)wv * 8) * 512 + lane * 8;
        f32x4 acc = {0.f, 0.f, 0.f, 0.f};
        #pragma unroll
        for (int kt = 0; kt < 8; kt++) {
            bf16x8 bfr = *(const bf16x8*)(wbase + kt * 512);
            acc = __builtin_amdgcn_mfma_f32_16x16x32_bf16(ah[kt], bfr, acc, 0, 0, 0);
        }
        float bias = bp[wv * 16 + fm];
        #pragma unroll
        for (int r_ = 0; r_ < 4; r_++) {
            int row = i0 + fq * 4 + r_;
            if (row < n) out[(size_t)row * 32 + wv * 16 + fm] = acc[r_] + bias;
        }
    }
}

// ---- proven round-5 fallback (only if ws too small) ----
__global__ __launch_bounds__(256) void nnlstm_fallback(
    const float* __restrict__ obs1, const float* __restrict__ obs2,
    const float* __restrict__ h,    const float* __restrict__ c,
    const float* __restrict__ Wemb, const float* __restrict__ bemb,
    const float* __restrict__ Wih,  const float* __restrict__ bih,
    const float* __restrict__ Whh,  const float* __restrict__ bhh,
    const float* __restrict__ Wp,   const float* __restrict__ bp,
    int n, float* __restrict__ out)
{
    __shared__ float sMd[16][64];
    __shared__ int   sMj[16][64];
    __shared__ float sX[16][292];
    __shared__ float sH[16][264];

    const int t   = threadIdx.x;
    const int sub = t & 15;
    const int ii  = t >> 4;
    const int i0  = blockIdx.x * 16;
    const int i   = i0 + ii;

    for (int v = t; v < 16 * 256; v += 256) {
        int r = v >> 8, k = v & 255;
        int row = i0 + r;
        sX[r][32 + k] = (row < n) ? h[(size_t)row * 256 + k] : 0.0f;
    }

    float bd0 = 1e30f, bd1 = 1e30f, bd2 = 1e30f, bd3 = 1e30f;
    int   bj0 = 0x7fffffff, bj1 = 0x7fffffff, bj2 = 0x7fffffff, bj3 = 0x7fffffff;

    if (i < n) {
        const float pix = obs2[2 * i];
        const float piy = obs2[2 * i + 1];
        for (int j = sub; j < n; j += 16) {
            float dx = obs2[2 * j]     - pix;
            float dy = obs2[2 * j + 1] - piy;
            float d2 = __fadd_rn(__fmul_rn(dx, dx), __fmul_rn(dy, dy));
            float dist = __fsqrt_rn(d2);
            if (j == i) continue;
            INS4(dist, j);
        }
    }
    sMd[ii][sub * 4 + 0] = bd0;  sMj[ii][sub * 4 + 0] = bj0;
    sMd[ii][sub * 4 + 1] = bd1;  sMj[ii][sub * 4 + 1] = bj1;
    sMd[ii][sub * 4 + 2] = bd2;  sMj[ii][sub * 4 + 2] = bj2;
    sMd[ii][sub * 4 + 3] = bd3;  sMj[ii][sub * 4 + 3] = bj3;
    __syncthreads();

    if (t < 16) {
        const int r = t;
        const int irow = i0 + r;
        float bd0 = 1e30f, bd1 = 1e30f, bd2 = 1e30f, bd3 = 1e30f;
        int   bj0 = 0x7fffffff, bj1 = 0x7fffffff, bj2 = 0x7fffffff, bj3 = 0x7fffffff;
        for (int q = 0; q < 64; q++) { INS4(sMd[r][q], sMj[r][q]); }

        if (irow < n) {
            float pix = obs2[2 * irow], piy = obs2[2 * irow + 1];
            float vix = pix - obs1[2 * irow];
            float viy = piy - obs1[2 * irow + 1];
            #pragma unroll
            for (int q2 = 0; q2 < 4; q2++) {
                int jn = (q2 == 0) ? bj0 : (q2 == 1) ? bj1 : (q2 == 2) ? bj2 : bj3;
                if (jn < 0 || jn >= n) jn = 0;
                float pjx = obs2[2 * jn], pjy = obs2[2 * jn + 1];
                float px = pjx - pix, py = pjy - piy;
                float vx = (pjx - obs1[2 * jn])     - vix;
                float vy = (pjy - obs1[2 * jn + 1]) - viy;
                #pragma unroll
                for (int e = 0; e < 8; e++) {
                    float a = px * Wemb[e]      + py * Wemb[8 + e]
                            + vx * Wemb[16 + e] + vy * Wemb[24 + e]
                            + bemb[e];
                    sX[r][q2 * 8 + e] = fmaxf(a, 0.0f);
                }
            }
        } else {
            for (int e = 0; e < 32; e++) sX[r][e] = 0.0f;
        }
    }
    __syncthreads();

    const int uu = t;
    float acc[4][16];
    #pragma unroll
    for (int j = 0; j < 4; j++) {
        float b = bih[uu + 256 * j] + bhh[uu + 256 * j];
        #pragma unroll
        for (int r = 0; r < 16; r++) acc[j][r] = b;
    }

    for (int kc = 0; kc < 288; kc++) {
        float w[4];
        #pragma unroll
        for (int j = 0; j < 4; j++) {
            int g = uu + 256 * j;
            w[j] = (kc < 32) ? Wih[(size_t)g * 32 + kc]
                             : Whh[(size_t)g * 256 + (kc - 32)];
        }
        #pragma unroll
        for (int r = 0; r < 16; r++) {
            float x = sX[r][kc];
            #pragma unroll
            for (int j = 0; j < 4; j++) acc[j][r] += w[j] * x;
        }
    }

    for (int r = 0; r < 16; r++) {
        int row = i0 + r;
        float cin = (row < n) ? c[(size_t)row * 256 + uu] : 0.0f;
        float cn = sigf(acc[1][r]) * cin + sigf(acc[0][r]) * tanhf(acc[2][r]);
        float hn = sigf(acc[3][r]) * tanhf(cn);
        sH[r][uu] = hn;
    }
    __syncthreads();

    for (int v = t; v < 16 * 32; v += 256) {
        int r = v >> 5, o = v & 31;
        int row = i0 + r;
        if (row >= n) continue;
        float a = bp[o];
        for (int kc = 0; kc < 256; kc++)
            a += Wp[(size_t)o * 256 + kc] * sH[r][kc];
        out[(size_t)row * 32 + o] = a;
    }
}

extern "C" void kernel_launch(void* const* d_in, const int* in_sizes, int n_in,
                              void* d_out, int out_size, void* d_ws, size_t ws_size,
                              hipStream_t stream) {
    float* out = (float*)d_out;

    int code = 0, n = 0;
    if (n_in != 12) code = 1;
    else {
        n = in_sizes[1] / 2;
        if (n <= 4 || in_sizes[1] != 2 * n)          code = 2;
        else if (in_sizes[0]  != 2 * n)              code = 3;
        else if (in_sizes[2]  != 256 * n)            code = 4;
        else if (in_sizes[3]  != 256 * n)            code = 5;
        else if (in_sizes[4]  != 32 || in_sizes[5] != 8)        code = 6;
        else if (in_sizes[6]  != 32768 || in_sizes[7] != 1024)  code = 7;
        else if (in_sizes[8]  != 262144 || in_sizes[9] != 1024) code = 8;
        else if (in_sizes[10] != 8192 || in_sizes[11] != 32)    code = 9;
        else if (out_size != 32 * n)                 code = 10;
    }
    if (code != 0) {
        diag_kernel<<<1, 1, 0, stream>>>(out, code, out_size);
        return;
    }

    const float* obs1   = (const float*)d_in[0];
    const float* obs2   = (const float*)d_in[1];
    const float* h      = (const float*)d_in[2];
    const float* c      = (const float*)d_in[3];
    const float* W_emb  = (const float*)d_in[4];
    const float* b_emb  = (const float*)d_in[5];
    const float* W_ih   = (const float*)d_in[6];
    const float* b_ih   = (const float*)d_in[7];
    const float* W_hh   = (const float*)d_in[8];
    const float* b_hh   = (const float*)d_in[9];
    const float* W_pool = (const float*)d_in[10];
    const float* b_pool = (const float*)d_in[11];

    const size_t wgf_bytes = (size_t)36864 * 8 * sizeof(u16);   // 589,824
    const size_t wpf_bytes = (size_t)1024 * 8 * sizeof(u16);    //  16,384

    if (ws_size >= wgf_bytes + wpf_bytes && n <= (1 << 24)) {
        u16* Wgf = (u16*)d_ws;
        u16* Wpf = (u16*)((char*)d_ws + wgf_bytes);
        int knn_blocks = (n + 3) / 4;
        knn_prep_kernel<<<knn_blocks + 148, 256, 0, stream>>>(
            obs1, obs2, W_emb, b_emb, W_ih, W_hh, W_pool, Wgf, Wpf,
            n, knn_blocks, out);
        lstm_kernel<<<(n + 15) / 16, 1024, 0, stream>>>(
            h, c, Wgf, b_ih, b_hh, Wpf, b_pool, n, out);
    } else {
        nnlstm_fallback<<<(n + 15) / 16, 256, 0, stream>>>(
            obs1, obs2, h, c, W_emb, b_emb, W_ih, b_ih, W_hh, b_hh,
            W_pool, b_pool, n, out);
    }
}

// Round 16
// 147.787 us; speedup vs baseline: 1.0003x; 1.0003x over previous
//
#include <hip/hip_runtime.h>
#include <hip/hip_cooperative_groups.h>
#include <math.h>

namespace cg = cooperative_groups;

typedef unsigned short u16;
typedef unsigned long long u64;
typedef __attribute__((ext_vector_type(8))) short bf16x8;
typedef __attribute__((ext_vector_type(4))) float f32x4;

__device__ __forceinline__ float sigf(float x)  { return 1.0f / (1.0f + __expf(-x)); }
__device__ __forceinline__ float tanhf_(float x){ float e = __expf(2.0f * x); return 1.0f - 2.0f / (e + 1.0f); }
__device__ __forceinline__ u16 f2bf(float f) {
    unsigned x = __float_as_uint(f);
    return (u16)((x + 0x7fffu + ((x >> 16) & 1u)) >> 16);
}

// u64-key sorted insert: keys k0<=k1<=k2<=k3, key = (asuint(d2)<<24)|idx.
// (d2,idx) order == np's (dist,idx) order — verified bit-identical in r14.
#define INSU(KEY) do {                                                              \
    u64 _k = (KEY);                                                                 \
    k3 = (_k < k3) ? _k : k3;                                                       \
    { bool _c = k3 < k2; u64 _lo = _c ? k3 : k2, _hi = _c ? k2 : k3; k2 = _lo; k3 = _hi; } \
    { bool _c = k2 < k1; u64 _lo = _c ? k2 : k1, _hi = _c ? k1 : k2; k1 = _lo; k2 = _hi; } \
    { bool _c = k1 < k0; u64 _lo = _c ? k1 : k0, _hi = _c ? k0 : k1; k0 = _lo; k1 = _hi; } \
} while (0)

#define INS4(D, J) do {                                                              \
    float _d = (D); int _j = (J);                                                    \
    if (_d < bd3 || (_d == bd3 && _j < bj3)) {                                       \
        bd3 = _d; bj3 = _j;                                                          \
        if (bd3 < bd2 || (bd3 == bd2 && bj3 < bj2)) {                                \
            float _t = bd2; bd2 = bd3; bd3 = _t; int _u = bj2; bj2 = bj3; bj3 = _u; }\
        if (bd2 < bd1 || (bd2 == bd1 && bj2 < bj1)) {                                \
            float _t = bd1; bd1 = bd2; bd2 = _t; int _u = bj1; bj1 = bj2; bj2 = _u; }\
        if (bd1 < bd0 || (bd1 == bd0 && bj1 < bj0)) {                                \
            float _t = bd0; bd0 = bd1; bd1 = _t; int _u = bj0; bj0 = bj1; bj1 = _u; }\
    } } while (0)

__global__ void diag_kernel(float* out, int code, int out_size) {
    if (out_size > 0) out[0] = (float)code * 1.0e8f;
}

__device__ __forceinline__ void prep_item(
    int id, const float* Wih, const float* Whh, const float* Wp,
    u16* Wgf, u16* Wpf)
{
    if (id < 36864) {                        // gates: 64 gt * 9 kt * 64 lanes
        int gt = id / 576, rem = id - gt * 576;
        int kt = rem >> 6, ln = rem & 63;
        int g  = gt * 16 + (ln & 15);
        int k  = kt * 32 + (ln >> 4) * 8;
        u16* dst = Wgf + (size_t)id * 8;
        #pragma unroll
        for (int j = 0; j < 8; j++) {
            int kk = k + j;
            float v = (kk < 32) ? Wih[(size_t)g * 32 + kk]
                                : Whh[(size_t)g * 256 + (kk - 32)];
            dst[j] = f2bf(v);
        }
    } else if (id < 37888) {                 // pool: 2 pt * 8 kt * 64 lanes
        int id2 = id - 36864;
        int pt = id2 >> 9, rem = id2 & 511;
        int kt = rem >> 6, ln = rem & 63;
        int o  = pt * 16 + (ln & 15);
        int k  = kt * 32 + (ln >> 4) * 8;
        u16* dst = Wpf + (size_t)id2 * 8;
        #pragma unroll
        for (int j = 0; j < 8; j++)
            dst[j] = f2bf(Wp[(size_t)o * 256 + k + j]);
    }
}

// Single cooperative kernel. Grid = knn_blocks (>=148 for the target shape).
// Phase A (all blocks): prep (blocks<148) + kNN top-4 (1 ped/wave, d2-keys,
// butterfly merge) + emb -> out (fp32). grid.sync(). Phase B (blocks < n/16):
// gates MFMA + LSTM + pool MFMA, 4 waves x 4 unit-tiles.
// __launch_bounds__(256,6): <=85 VGPR -> 6 blocks/CU -> 1536 blocks co-resident.
__global__ __launch_bounds__(256, 6) void coop_kernel(
    const float* __restrict__ obs1, const float* __restrict__ obs2,
    const float* __restrict__ h,    const float* __restrict__ c,
    const float* __restrict__ Wemb, const float* __restrict__ bemb,
    const float* __restrict__ Wih,  const float* __restrict__ Whh,
    const float* __restrict__ Wp,
    const float* __restrict__ bih,  const float* __restrict__ bhh,
    const float* __restrict__ bp,
    u16* __restrict__ Wgf, u16* __restrict__ Wpf,
    int n, int knn_blocks, float* __restrict__ out)
{
    __shared__ __align__(16) char lds[17920];
    u16* sXb = (u16*)lds;                     // [16][296] bf16 X=[emb|h]
    u16* sHb = (u16*)(lds + 9472);            // [16][264] bf16 h_new

    const int t    = threadIdx.x;
    const int lane = t & 63;
    const int wv   = t >> 6;
    const int fm   = lane & 15;
    const int fq   = lane >> 4;

    // ---- prep (blocks < 148 cover all 37888 items with id = b*256+t) ----
    if (blockIdx.x < 148) {
        int id = blockIdx.x * 256 + t;
        prep_item(id, Wih, Whh, Wp, Wgf, Wpf);
    }

    // ---- Phase A: kNN scan, 1 ped/wave (r14 K1 verbatim) ----
    {
        const int i = blockIdx.x * 4 + wv;
        if (blockIdx.x < knn_blocks && i < n) {
            const float2* o2 = (const float2*)obs2;
            const float2 pi = o2[i];

            u64 k0 = ~0ull, k1 = ~0ull, k2 = ~0ull, k3 = ~0ull;

            int j = lane;
            for (; j + 192 < n; j += 256) {
                float2 p0 = o2[j], p1 = o2[j + 64], p2 = o2[j + 128], p3 = o2[j + 192];
                float dx, dy, d2; u64 key;
                dx = p0.x - pi.x; dy = p0.y - pi.y;
                d2 = __fadd_rn(__fmul_rn(dx, dx), __fmul_rn(dy, dy));
                key = (((u64)__float_as_uint(d2)) << 24) | (unsigned)j;
                key = (j == i) ? ~0ull : key;                         INSU(key);
                dx = p1.x - pi.x; dy = p1.y - pi.y;
                d2 = __fadd_rn(__fmul_rn(dx, dx), __fmul_rn(dy, dy));
                key = (((u64)__float_as_uint(d2)) << 24) | (unsigned)(j + 64);
                key = (j + 64 == i) ? ~0ull : key;                    INSU(key);
                dx = p2.x - pi.x; dy = p2.y - pi.y;
                d2 = __fadd_rn(__fmul_rn(dx, dx), __fmul_rn(dy, dy));
                key = (((u64)__float_as_uint(d2)) << 24) | (unsigned)(j + 128);
                key = (j + 128 == i) ? ~0ull : key;                   INSU(key);
                dx = p3.x - pi.x; dy = p3.y - pi.y;
                d2 = __fadd_rn(__fmul_rn(dx, dx), __fmul_rn(dy, dy));
                key = (((u64)__float_as_uint(d2)) << 24) | (unsigned)(j + 192);
                key = (j + 192 == i) ? ~0ull : key;                   INSU(key);
            }
            for (; j < n; j += 64) {
                float2 pj = o2[j];
                float dx = pj.x - pi.x, dy = pj.y - pi.y;
                float d2 = __fadd_rn(__fmul_rn(dx, dx), __fmul_rn(dy, dy));
                u64 key = (((u64)__float_as_uint(d2)) << 24) | (unsigned)j;
                key = (j == i) ? ~0ull : key;
                INSU(key);
            }

            #pragma unroll
            for (int m = 1; m < 64; m <<= 1) {
                u64 o0 = __shfl_xor(k0, m), o1 = __shfl_xor(k1, m);
                u64 o2_ = __shfl_xor(k2, m), o3 = __shfl_xor(k3, m);
                INSU(o0); INSU(o1); INSU(o2_); INSU(o3);
            }

            if (lane < 4) {
                u64 kq = (lane == 0) ? k0 : (lane == 1) ? k1 : (lane == 2) ? k2 : k3;
                int jn = (int)(kq & 0xFFFFFF);
                if (jn < 0 || jn >= n) jn = 0;
                float pix = pi.x, piy = pi.y;
                float pjx = obs2[2 * jn], pjy = obs2[2 * jn + 1];
                float px = pjx - pix, py = pjy - piy;
                float vix = pix - obs1[2 * i];
                float viy = piy - obs1[2 * i + 1];
                float vx = (pjx - obs1[2 * jn])     - vix;
                float vy = (pjy - obs1[2 * jn + 1]) - viy;
                float* dst = out + (size_t)i * 32 + lane * 8;
                #pragma unroll
                for (int e = 0; e < 8; e++) {
                    float a = px * Wemb[e]      + py * Wemb[8 + e]
                            + vx * Wemb[16 + e] + vy * Wemb[24 + e]
                            + bemb[e];
                    dst[e] = fmaxf(a, 0.0f);
                }
            }
        }
    }

    cg::this_grid().sync();   // emb + Wgf/Wpf visible to all blocks

    // ---- Phase B: blocks < ceil(n/16) run gates+LSTM+pool for 16 rows ----
    if (blockIdx.x >= (n + 15) / 16) return;
    const int i0 = blockIdx.x * 16;

    // stage emb (fp32 in out) -> sXb[:,0:32)
    for (int v = t; v < 512; v += 256) {
        int r = v >> 5, e = v & 31;
        int row = i0 + r;
        float val = (row < n) ? out[(size_t)row * 32 + e] : 0.0f;
        sXb[r * 296 + e] = f2bf(val);
    }
    // stage h -> sXb[:,32:288)
    for (int f = t; f < 1024; f += 256) {
        int r = f >> 6, k4 = f & 63;
        int row = i0 + r;
        float4 hv = (row < n) ? ((const float4*)h)[(size_t)row * 64 + k4]
                              : make_float4(0.f, 0.f, 0.f, 0.f);
        u16* d = &sXb[r * 296 + 32 + k4 * 4];
        d[0] = f2bf(hv.x); d[1] = f2bf(hv.y); d[2] = f2bf(hv.z); d[3] = f2bf(hv.w);
    }
    __syncthreads();

    // A-frags: lane holds X[row=fm][kt*32 + fq*8 + j]
    bf16x8 afr[9];
    #pragma unroll
    for (int kt = 0; kt < 9; kt++)
        afr[kt] = *(const bf16x8*)&sXb[fm * 296 + kt * 32 + fq * 8];

    // gates + pointwise: wave wv covers unit tiles 4wv..4wv+3
    #pragma unroll
    for (int ut2 = 0; ut2 < 4; ut2++) {
        const int ut = wv * 4 + ut2;
        const int u  = ut * 16 + fm;

        f32x4 acc[4];
        #pragma unroll
        for (int jg = 0; jg < 4; jg++) acc[jg] = (f32x4){0.f, 0.f, 0.f, 0.f};

        #pragma unroll
        for (int jg = 0; jg < 4; jg++) {      // gate type i,f,g,o
            const int gt = jg * 16 + ut;
            const u16* wbase = Wgf + ((size_t)gt * 9) * 512 + lane * 8;
            #pragma unroll
            for (int kt = 0; kt < 9; kt++) {
                bf16x8 bfr = *(const bf16x8*)(wbase + kt * 512);  // coalesced 1 KB
                acc[jg] = __builtin_amdgcn_mfma_f32_16x16x32_bf16(afr[kt], bfr, acc[jg], 0, 0, 0);
            }
        }

        float b0 = bih[u]       + bhh[u];
        float b1 = bih[u + 256] + bhh[u + 256];
        float b2 = bih[u + 512] + bhh[u + 512];
        float b3 = bih[u + 768] + bhh[u + 768];

        #pragma unroll
        for (int r_ = 0; r_ < 4; r_++) {      // D-layout: row = fq*4 + r_
            int row = i0 + fq * 4 + r_;
            float cin = (row < n) ? c[(size_t)row * 256 + u] : 0.0f;
            float gi = acc[0][r_] + b0;
            float gf = acc[1][r_] + b1;
            float gg = acc[2][r_] + b2;
            float go = acc[3][r_] + b3;
            float cn = sigf(gf) * cin + sigf(gi) * tanhf_(gg);
            float hn = sigf(go) * tanhf_(cn);
            sHb[(fq * 4 + r_) * 264 + u] = f2bf(hn);
        }
    }
    __syncthreads();

    // pool GEMM: M=16 x N=32 x K=256; waves 0,1 take one n-tile each
    if (wv < 2) {
        bf16x8 ah[8];
        #pragma unroll
        for (int kt = 0; kt < 8; kt++)
            ah[kt] = *(const bf16x8*)&sHb[fm * 264 + kt * 32 + fq * 8];
        const u16* wbase = Wpf + ((size_t)wv * 8) * 512 + lane * 8;
        f32x4 acc = {0.f, 0.f, 0.f, 0.f};
        #pragma unroll
        for (int kt = 0; kt < 8; kt++) {
            bf16x8 bfr = *(const bf16x8*)(wbase + kt * 512);
            acc = __builtin_amdgcn_mfma_f32_16x16x32_bf16(ah[kt], bfr, acc, 0, 0, 0);
        }
        float bias = bp[wv * 16 + fm];
        #pragma unroll
        for (int r_ = 0; r_ < 4; r_++) {
            int row = i0 + fq * 4 + r_;
            if (row < n) out[(size_t)row * 32 + wv * 16 + fm] = acc[r_] + bias;
        }
    }
}

// ---- r15 two-dispatch path (fallback if cooperative launch unavailable) ----
__global__ __launch_bounds__(256) void knn_prep_kernel(
    const float* __restrict__ obs1, const float* __restrict__ obs2,
    const float* __restrict__ Wemb, const float* __restrict__ bemb,
    const float* __restrict__ Wih,  const float* __restrict__ Whh,
    const float* __restrict__ Wp,
    u16* __restrict__ Wgf, u16* __restrict__ Wpf,
    int n, int knn_blocks, float* __restrict__ out)
{
    const int t = threadIdx.x;

    if (blockIdx.x >= knn_blocks) {
        int id = (blockIdx.x - knn_blocks) * 256 + t;
        prep_item(id, Wih, Whh, Wp, Wgf, Wpf);
        return;
    }

    const int lane = t & 63;
    const int wv   = t >> 6;
    const int i    = blockIdx.x * 4 + wv;
    if (i >= n) return;

    const float2* o2 = (const float2*)obs2;
    const float2 pi = o2[i];

    u64 k0 = ~0ull, k1 = ~0ull, k2 = ~0ull, k3 = ~0ull;

    int j = lane;
    for (; j + 192 < n; j += 256) {
        float2 p0 = o2[j], p1 = o2[j + 64], p2 = o2[j + 128], p3 = o2[j + 192];
        float dx, dy, d2; u64 key;
        dx = p0.x - pi.x; dy = p0.y - pi.y;
        d2 = __fadd_rn(__fmul_rn(dx, dx), __fmul_rn(dy, dy));
        key = (((u64)__float_as_uint(d2)) << 24) | (unsigned)j;
        key = (j == i) ? ~0ull : key;                         INSU(key);
        dx = p1.x - pi.x; dy = p1.y - pi.y;
        d2 = __fadd_rn(__fmul_rn(dx, dx), __fmul_rn(dy, dy));
        key = (((u64)__float_as_uint(d2)) << 24) | (unsigned)(j + 64);
        key = (j + 64 == i) ? ~0ull : key;                    INSU(key);
        dx = p2.x - pi.x; dy = p2.y - pi.y;
        d2 = __fadd_rn(__fmul_rn(dx, dx), __fmul_rn(dy, dy));
        key = (((u64)__float_as_uint(d2)) << 24) | (unsigned)(j + 128);
        key = (j + 128 == i) ? ~0ull : key;                   INSU(key);
        dx = p3.x - pi.x; dy = p3.y - pi.y;
        d2 = __fadd_rn(__fmul_rn(dx, dx), __fmul_rn(dy, dy));
        key = (((u64)__float_as_uint(d2)) << 24) | (unsigned)(j + 192);
        key = (j + 192 == i) ? ~0ull : key;                   INSU(key);
    }
    for (; j < n; j += 64) {
        float2 pj = o2[j];
        float dx = pj.x - pi.x, dy = pj.y - pi.y;
        float d2 = __fadd_rn(__fmul_rn(dx, dx), __fmul_rn(dy, dy));
        u64 key = (((u64)__float_as_uint(d2)) << 24) | (unsigned)j;
        key = (j == i) ? ~0ull : key;
        INSU(key);
    }

    #pragma unroll
    for (int m = 1; m < 64; m <<= 1) {
        u64 o0 = __shfl_xor(k0, m), o1 = __shfl_xor(k1, m);
        u64 o2_ = __shfl_xor(k2, m), o3 = __shfl_xor(k3, m);
        INSU(o0); INSU(o1); INSU(o2_); INSU(o3);
    }

    if (lane < 4) {
        u64 kq = (lane == 0) ? k0 : (lane == 1) ? k1 : (lane == 2) ? k2 : k3;
        int jn = (int)(kq & 0xFFFFFF);
        if (jn < 0 || jn >= n) jn = 0;
        float pix = pi.x, piy = pi.y;
        float pjx = obs2[2 * jn], pjy = obs2[2 * jn + 1];
        float px = pjx - pix, py = pjy - piy;
        float vix = pix - obs1[2 * i];
        float viy = piy - obs1[2 * i + 1];
        float vx = (pjx - obs1[2 * jn])     - vix;
        float vy = (pjy - obs1[2 * jn + 1]) - viy;
        float* dst = out + (size_t)i * 32 + lane * 8;
        #pragma unroll
        for (int e = 0; e < 8; e++) {
            float a = px * Wemb[e]      + py * Wemb[8 + e]
                    + vx * Wemb[16 + e] + vy * Wemb[24 + e]
                    + bemb[e];
            dst[e] = fmaxf(a, 0.0f);
        }
    }
}

__global__ __launch_bounds__(1024) void lstm_kernel(
    const float* __restrict__ h,   const float* __restrict__ c,
    const u16*  __restrict__ Wgf,  const float* __restrict__ bih,
    const float* __restrict__ bhh,
    const u16*  __restrict__ Wpf,  const float* __restrict__ bp,
    int n, float* __restrict__ out)
{
    __shared__ __align__(16) char lds[17920];
    u16* sXb = (u16*)lds;
    u16* sHb = (u16*)(lds + 9472);

    const int t    = threadIdx.x;
    const int i0   = blockIdx.x * 16;
    const int lane = t & 63;
    const int wv   = t >> 6;
    const int fm   = lane & 15;
    const int fq   = lane >> 4;

    if (t < 512) {
        int r = t >> 5, e = t & 31;
        int row = i0 + r;
        float v = (row < n) ? out[(size_t)row * 32 + e] : 0.0f;
        sXb[r * 296 + e] = f2bf(v);
    }
    {
        int r = t >> 6, k4 = t & 63;
        int row = i0 + r;
        float4 hv = (row < n) ? ((const float4*)h)[(size_t)row * 64 + k4]
                              : make_float4(0.f, 0.f, 0.f, 0.f);
        u16* d = &sXb[r * 296 + 32 + k4 * 4];
        d[0] = f2bf(hv.x); d[1] = f2bf(hv.y); d[2] = f2bf(hv.z); d[3] = f2bf(hv.w);
    }
    __syncthreads();

    bf16x8 afr[9];
    #pragma unroll
    for (int kt = 0; kt < 9; kt++)
        afr[kt] = *(const bf16x8*)&sXb[fm * 296 + kt * 32 + fq * 8];

    {
        const int ut = wv;
        const int u  = ut * 16 + fm;

        f32x4 acc[4];
        #pragma unroll
        for (int jg = 0; jg < 4; jg++) acc[jg] = (f32x4){0.f, 0.f, 0.f, 0.f};

        #pragma unroll
        for (int jg = 0; jg < 4; jg++) {
            const int gt = jg * 16 + ut;
            const u16* wbase = Wgf + ((size_t)gt * 9) * 512 + lane * 8;
            #pragma unroll
            for (int kt = 0; kt < 9; kt++) {
                bf16x8 bfr = *(const bf16x8*)(wbase + kt * 512);
                acc[jg] = __builtin_amdgcn_mfma_f32_16x16x32_bf16(afr[kt], bfr, acc[jg], 0, 0, 0);
            }
        }

        float b0 = bih[u]       + bhh[u];
        float b1 = bih[u + 256] + bhh[u + 256];
        float b2 = bih[u + 512] + bhh[u + 512];
        float b3 = bih[u + 768] + bhh[u + 768];

        #pragma unroll
        for (int r_ = 0; r_ < 4; r_++) {
            int row = i0 + fq * 4 + r_;
            float cin = (row < n) ? c[(size_t)row * 256 + u] : 0.0f;
            float gi = acc[0][r_] + b0;
            float gf = acc[1][r_] + b1;
            float gg = acc[2][r_] + b2;
            float go = acc[3][r_] + b3;
            float cn = sigf(gf) * cin + sigf(gi) * tanhf_(gg);
            float hn = sigf(go) * tanhf_(cn);
            sHb[(fq * 4 + r_) * 264 + u] = f2bf(hn);
        }
    }
    __syncthreads();

    if (wv < 2) {
        bf16x8 ah[8];
        #pragma unroll
        for (int kt = 0; kt < 8; kt++)
            ah[kt] = *(const bf16x8*)&sHb[fm * 264 + kt * 32 + fq * 8];
        const u16* wbase = Wpf + ((size_t)wv * 8) * 512 + lane * 8;
        f32x4 acc = {0.f, 0.f, 0.f, 0.f};
        #pragma unroll
        for (int kt = 0; kt < 8; kt++) {
            bf16x8 bfr = *(const bf16x8*)(wbase + kt * 512);
            acc = __builtin_amdgcn_mfma_f32_16x16x32_bf16(ah[kt], bfr, acc, 0, 0, 0);
        }
        float bias = bp[wv * 16 + fm];
        #pragma unroll
        for (int r_ = 0; r_ < 4; r_++) {
            int row = i0 + fq * 4 + r_;
            if (row < n) out[(size_t)row * 32 + wv * 16 + fm] = acc[r_] + bias;
        }
    }
}

// ---- round-5 fallback (no workspace) ----
__global__ __launch_bounds__(256) void nnlstm_fallback(
    const float* __restrict__ obs1, const float* __restrict__ obs2,
    const float* __restrict__ h,    const float* __restrict__ c,
    const float* __restrict__ Wemb, const float* __restrict__ bemb,
    const float* __restrict__ Wih,  const float* __restrict__ bih,
    const float* __restrict__ Whh,  const float* __restrict__ bhh,
    const float* __restrict__ Wp,   const float* __restrict__ bp,
    int n, float* __restrict__ out)
{
    __shared__ float sMd[16][64];
    __shared__ int   sMj[16][64];
    __shared__ float sX[16][292];
    __shared__ float sH[16][264];

    const int t   = threadIdx.x;
    const int sub = t & 15;
    const int ii  = t >> 4;
    const int i0  = blockIdx.x * 16;
    const int i   = i0 + ii;

    for (int v = t; v < 16 * 256; v += 256) {
        int r = v >> 8, k = v & 255;
        int row = i0 + r;
        sX[r][32 + k] = (row < n) ? h[(size_t)row * 256 + k] : 0.0f;
    }

    float bd0 = 1e30f, bd1 = 1e30f, bd2 = 1e30f, bd3 = 1e30f;
    int   bj0 = 0x7fffffff, bj1 = 0x7fffffff, bj2 = 0x7fffffff, bj3 = 0x7fffffff;

    if (i < n) {
        const float pix = obs2[2 * i];
        const float piy = obs2[2 * i + 1];
        for (int j = sub; j < n; j += 16) {
            float dx = obs2[2 * j]     - pix;
            float dy = obs2[2 * j + 1] - piy;
            float d2 = __fadd_rn(__fmul_rn(dx, dx), __fmul_rn(dy, dy));
            float dist = __fsqrt_rn(d2);
            if (j == i) continue;
            INS4(dist, j);
        }
    }
    sMd[ii][sub * 4 + 0] = bd0;  sMj[ii][sub * 4 + 0] = bj0;
    sMd[ii][sub * 4 + 1] = bd1;  sMj[ii][sub * 4 + 1] = bj1;
    sMd[ii][sub * 4 + 2] = bd2;  sMj[ii][sub * 4 + 2] = bj2;
    sMd[ii][sub * 4 + 3] = bd3;  sMj[ii][sub * 4 + 3] = bj3;
    __syncthreads();

    if (t < 16) {
        const int r = t;
        const int irow = i0 + r;
        float bd0 = 1e30f, bd1 = 1e30f, bd2 = 1e30f, bd3 = 1e30f;
        int   bj0 = 0x7fffffff, bj1 = 0x7fffffff, bj2 = 0x7fffffff, bj3 = 0x7fffffff;
        for (int q = 0; q < 64; q++) { INS4(sMd[r][q], sMj[r][q]); }

        if (irow < n) {
            float pix = obs2[2 * irow], piy = obs2[2 * irow + 1];
            float vix = pix - obs1[2 * irow];
            float viy = piy - obs1[2 * irow + 1];
            #pragma unroll
            for (int q2 = 0; q2 < 4; q2++) {
                int jn = (q2 == 0) ? bj0 : (q2 == 1) ? bj1 : (q2 == 2) ? bj2 : bj3;
                if (jn < 0 || jn >= n) jn = 0;
                float pjx = obs2[2 * jn], pjy = obs2[2 * jn + 1];
                float px = pjx - pix, py = pjy - piy;
                float vx = (pjx - obs1[2 * jn])     - vix;
                float vy = (pjy - obs1[2 * jn + 1]) - viy;
                #pragma unroll
                for (int e = 0; e < 8; e++) {
                    float a = px * Wemb[e]      + py * Wemb[8 + e]
                            + vx * Wemb[16 + e] + vy * Wemb[24 + e]
                            + bemb[e];
                    sX[r][q2 * 8 + e] = fmaxf(a, 0.0f);
                }
            }
        } else {
            for (int e = 0; e < 32; e++) sX[r][e] = 0.0f;
        }
    }
    __syncthreads();

    const int uu = t;
    float acc[4][16];
    #pragma unroll
    for (int j = 0; j < 4; j++) {
        float b = bih[uu + 256 * j] + bhh[uu + 256 * j];
        #pragma unroll
        for (int r = 0; r < 16; r++) acc[j][r] = b;
    }

    for (int kc = 0; kc < 288; kc++) {
        float w[4];
        #pragma unroll
        for (int j = 0; j < 4; j++) {
            int g = uu + 256 * j;
            w[j] = (kc < 32) ? Wih[(size_t)g * 32 + kc]
                             : Whh[(size_t)g * 256 + (kc - 32)];
        }
        #pragma unroll
        for (int r = 0; r < 16; r++) {
            float x = sX[r][kc];
            #pragma unroll
            for (int j = 0; j < 4; j++) acc[j][r] += w[j] * x;
        }
    }

    for (int r = 0; r < 16; r++) {
        int row = i0 + r;
        float cin = (row < n) ? c[(size_t)row * 256 + uu] : 0.0f;
        float cn = sigf(acc[1][r]) * cin + sigf(acc[0][r]) * tanhf(acc[2][r]);
        float hn = sigf(acc[3][r]) * tanhf(cn);
        sH[r][uu] = hn;
    }
    __syncthreads();

    for (int v = t; v < 16 * 32; v += 256) {
        int r = v >> 5, o = v & 31;
        int row = i0 + r;
        if (row >= n) continue;
        float a = bp[o];
        for (int kc = 0; kc < 256; kc++)
            a += Wp[(size_t)o * 256 + kc] * sH[r][kc];
        out[(size_t)row * 32 + o] = a;
    }
}

extern "C" void kernel_launch(void* const* d_in, const int* in_sizes, int n_in,
                              void* d_out, int out_size, void* d_ws, size_t ws_size,
                              hipStream_t stream) {
    float* out = (float*)d_out;

    int code = 0, n = 0;
    if (n_in != 12) code = 1;
    else {
        n = in_sizes[1] / 2;
        if (n <= 4 || in_sizes[1] != 2 * n)          code = 2;
        else if (in_sizes[0]  != 2 * n)              code = 3;
        else if (in_sizes[2]  != 256 * n)            code = 4;
        else if (in_sizes[3]  != 256 * n)            code = 5;
        else if (in_sizes[4]  != 32 || in_sizes[5] != 8)        code = 6;
        else if (in_sizes[6]  != 32768 || in_sizes[7] != 1024)  code = 7;
        else if (in_sizes[8]  != 262144 || in_sizes[9] != 1024) code = 8;
        else if (in_sizes[10] != 8192 || in_sizes[11] != 32)    code = 9;
        else if (out_size != 32 * n)                 code = 10;
    }
    if (code != 0) {
        diag_kernel<<<1, 1, 0, stream>>>(out, code, out_size);
        return;
    }

    const float* obs1   = (const float*)d_in[0];
    const float* obs2   = (const float*)d_in[1];
    const float* h      = (const float*)d_in[2];
    const float* c      = (const float*)d_in[3];
    const float* W_emb  = (const float*)d_in[4];
    const float* b_emb  = (const float*)d_in[5];
    const float* W_ih   = (const float*)d_in[6];
    const float* b_ih   = (const float*)d_in[7];
    const float* W_hh   = (const float*)d_in[8];
    const float* b_hh   = (const float*)d_in[9];
    const float* W_pool = (const float*)d_in[10];
    const float* b_pool = (const float*)d_in[11];

    const size_t wgf_bytes = (size_t)36864 * 8 * sizeof(u16);   // 589,824
    const size_t wpf_bytes = (size_t)1024 * 8 * sizeof(u16);    //  16,384

    if (!(ws_size >= wgf_bytes + wpf_bytes && n <= (1 << 24))) {
        nnlstm_fallback<<<(n + 15) / 16, 256, 0, stream>>>(
            obs1, obs2, h, c, W_emb, b_emb, W_ih, b_ih, W_hh, b_hh,
            W_pool, b_pool, n, out);
        return;
    }

    u16* Wgf = (u16*)d_ws;
    u16* Wpf = (u16*)((char*)d_ws + wgf_bytes);
    int knn_blocks = (n + 3) / 4;
    int grid = (knn_blocks > 148) ? knn_blocks : 148;

    // cooperative feasibility: all `grid` blocks must be co-resident
    bool coop_ok = false;
    {
        int occ = 0;
        hipDeviceProp_t prop;
        if (hipGetDeviceProperties(&prop, 0) == hipSuccess &&
            hipOccupancyMaxActiveBlocksPerMultiprocessor(
                &occ, (const void*)coop_kernel, 256, 0) == hipSuccess) {
            coop_ok = ((long long)occ * prop.multiProcessorCount >= grid);
        }
    }

    if (coop_ok) {
        void* args[] = {
            (void*)&obs1, (void*)&obs2, (void*)&h, (void*)&c,
            (void*)&W_emb, (void*)&b_emb,
            (void*)&W_ih, (void*)&W_hh, (void*)&W_pool,
            (void*)&b_ih, (void*)&b_hh, (void*)&b_pool,
            (void*)&Wgf, (void*)&Wpf,
            (void*)&n, (void*)&knn_blocks, (void*)&out
        };
        hipError_t le = hipLaunchCooperativeKernel(
            (void*)coop_kernel, dim3(grid), dim3(256), args, 0, stream);
        if (le == hipSuccess) return;
        // fall through to two-dispatch path on failure
    }

    knn_prep_kernel<<<knn_blocks + 148, 256, 0, stream>>>(
        obs1, obs2, W_emb, b_emb, W_ih, W_hh, W_pool, Wgf, Wpf,
        n, knn_blocks, out);
    lstm_kernel<<<(n + 15) / 16, 1024, 0, stream>>>(
        h, c, Wgf, b_ih, b_hh, Wpf, b_pool, n, out);
}

// Round 17
// 143.623 us; speedup vs baseline: 1.0293x; 1.0290x over previous
//
#include <hip/hip_runtime.h>
#include <math.h>

typedef unsigned short u16;
typedef unsigned long long u64;
typedef __attribute__((ext_vector_type(8))) short bf16x8;
typedef __attribute__((ext_vector_type(4))) float f32x4;

__device__ __forceinline__ float sigf(float x)  { return 1.0f / (1.0f + __expf(-x)); }
__device__ __forceinline__ float tanhf_(float x){ float e = __expf(2.0f * x); return 1.0f - 2.0f / (e + 1.0f); }
__device__ __forceinline__ u16 f2bf(float f) {
    unsigned x = __float_as_uint(f);
    return (u16)((x + 0x7fffu + ((x >> 16) & 1u)) >> 16);
}

// u64-key sorted insert: keys k0<=k1<=k2<=k3, key = (asuint(d2)<<24)|idx.
// (d2,idx) order == np's (dist,idx) order — verified bit-identical in r14.
#define INSU(KEY) do {                                                              \
    u64 _k = (KEY);                                                                 \
    k3 = (_k < k3) ? _k : k3;                                                       \
    { bool _c = k3 < k2; u64 _lo = _c ? k3 : k2, _hi = _c ? k2 : k3; k2 = _lo; k3 = _hi; } \
    { bool _c = k2 < k1; u64 _lo = _c ? k2 : k1, _hi = _c ? k1 : k2; k1 = _lo; k2 = _hi; } \
    { bool _c = k1 < k0; u64 _lo = _c ? k1 : k0, _hi = _c ? k0 : k1; k0 = _lo; k1 = _hi; } \
} while (0)

#define INS4(D, J) do {                                                              \
    float _d = (D); int _j = (J);                                                    \
    if (_d < bd3 || (_d == bd3 && _j < bj3)) {                                       \
        bd3 = _d; bj3 = _j;                                                          \
        if (bd3 < bd2 || (bd3 == bd2 && bj3 < bj2)) {                                \
            float _t = bd2; bd2 = bd3; bd3 = _t; int _u = bj2; bj2 = bj3; bj3 = _u; }\
        if (bd2 < bd1 || (bd2 == bd1 && bj2 < bj1)) {                                \
            float _t = bd1; bd1 = bd2; bd2 = _t; int _u = bj1; bj1 = bj2; bj2 = _u; }\
        if (bd1 < bd0 || (bd1 == bd0 && bj1 < bj0)) {                                \
            float _t = bd0; bd0 = bd1; bd1 = _t; int _u = bj0; bj0 = bj1; bj1 = _u; }\
    } } while (0)

__global__ void diag_kernel(float* out, int code, int out_size) {
    if (out_size > 0) out[0] = (float)code * 1.0e8f;
}

__device__ __forceinline__ void prep_item(
    int id, const float* Wih, const float* Whh, const float* Wp,
    u16* Wgf, u16* Wpf)
{
    if (id < 36864) {                        // gates: 64 gt * 9 kt * 64 lanes
        int gt = id / 576, rem = id - gt * 576;
        int kt = rem >> 6, ln = rem & 63;
        int g  = gt * 16 + (ln & 15);
        int k  = kt * 32 + (ln >> 4) * 8;
        u16* dst = Wgf + (size_t)id * 8;
        #pragma unroll
        for (int j = 0; j < 8; j++) {
            int kk = k + j;
            float v = (kk < 32) ? Wih[(size_t)g * 32 + kk]
                                : Whh[(size_t)g * 256 + (kk - 32)];
            dst[j] = f2bf(v);
        }
    } else if (id < 37888) {                 // pool: 2 pt * 8 kt * 64 lanes
        int id2 = id - 36864;
        int pt = id2 >> 9, rem = id2 & 511;
        int kt = rem >> 6, ln = rem & 63;
        int o  = pt * 16 + (ln & 15);
        int k  = kt * 32 + (ln >> 4) * 8;
        u16* dst = Wpf + (size_t)id2 * 8;
        #pragma unroll
        for (int j = 0; j < 8; j++)
            dst[j] = f2bf(Wp[(size_t)o * 256 + k + j]);
    }
}

// K1: blocks [0, knn_blocks): kNN top-4 + Linear(4,8)+ReLU emb -> out (fp32 [n,32]).
//     One WAVE per pedestrian; u64 packed d2-keys; shfl-xor butterfly merge.
//     blocks [knn_blocks, ...): bf16 weight prep (byte-identical to r14).
__global__ __launch_bounds__(256) void knn_prep_kernel(
    const float* __restrict__ obs1, const float* __restrict__ obs2,
    const float* __restrict__ Wemb, const float* __restrict__ bemb,
    const float* __restrict__ Wih,  const float* __restrict__ Whh,
    const float* __restrict__ Wp,
    u16* __restrict__ Wgf, u16* __restrict__ Wpf,
    int n, int knn_blocks, float* __restrict__ out)
{
    const int t = threadIdx.x;

    if (blockIdx.x >= knn_blocks) {
        int id = (blockIdx.x - knn_blocks) * 256 + t;
        prep_item(id, Wih, Whh, Wp, Wgf, Wpf);
        return;
    }

    const int lane = t & 63;
    const int wv   = t >> 6;
    const int i    = blockIdx.x * 4 + wv;
    if (i >= n) return;

    const float2* o2 = (const float2*)obs2;
    const float2 pi = o2[i];

    u64 k0 = ~0ull, k1 = ~0ull, k2 = ~0ull, k3 = ~0ull;

    int j = lane;
    for (; j + 192 < n; j += 256) {              // 4 coalesced 512B wave-loads in flight
        float2 p0 = o2[j], p1 = o2[j + 64], p2 = o2[j + 128], p3 = o2[j + 192];
        float dx, dy, d2; u64 key;
        dx = p0.x - pi.x; dy = p0.y - pi.y;
        d2 = __fadd_rn(__fmul_rn(dx, dx), __fmul_rn(dy, dy));
        key = (((u64)__float_as_uint(d2)) << 24) | (unsigned)j;
        key = (j == i) ? ~0ull : key;                         INSU(key);
        dx = p1.x - pi.x; dy = p1.y - pi.y;
        d2 = __fadd_rn(__fmul_rn(dx, dx), __fmul_rn(dy, dy));
        key = (((u64)__float_as_uint(d2)) << 24) | (unsigned)(j + 64);
        key = (j + 64 == i) ? ~0ull : key;                    INSU(key);
        dx = p2.x - pi.x; dy = p2.y - pi.y;
        d2 = __fadd_rn(__fmul_rn(dx, dx), __fmul_rn(dy, dy));
        key = (((u64)__float_as_uint(d2)) << 24) | (unsigned)(j + 128);
        key = (j + 128 == i) ? ~0ull : key;                   INSU(key);
        dx = p3.x - pi.x; dy = p3.y - pi.y;
        d2 = __fadd_rn(__fmul_rn(dx, dx), __fmul_rn(dy, dy));
        key = (((u64)__float_as_uint(d2)) << 24) | (unsigned)(j + 192);
        key = (j + 192 == i) ? ~0ull : key;                   INSU(key);
    }
    for (; j < n; j += 64) {
        float2 pj = o2[j];
        float dx = pj.x - pi.x, dy = pj.y - pi.y;
        float d2 = __fadd_rn(__fmul_rn(dx, dx), __fmul_rn(dy, dy));
        u64 key = (((u64)__float_as_uint(d2)) << 24) | (unsigned)j;
        key = (j == i) ? ~0ull : key;
        INSU(key);
    }

    #pragma unroll
    for (int m = 1; m < 64; m <<= 1) {
        u64 o0 = __shfl_xor(k0, m), o1 = __shfl_xor(k1, m);
        u64 o2_ = __shfl_xor(k2, m), o3 = __shfl_xor(k3, m);
        INSU(o0); INSU(o1); INSU(o2_); INSU(o3);
    }

    if (lane < 4) {
        u64 kq = (lane == 0) ? k0 : (lane == 1) ? k1 : (lane == 2) ? k2 : k3;
        int jn = (int)(kq & 0xFFFFFF);
        if (jn < 0 || jn >= n) jn = 0;
        float pix = pi.x, piy = pi.y;
        float pjx = obs2[2 * jn], pjy = obs2[2 * jn + 1];
        float px = pjx - pix, py = pjy - piy;
        float vix = pix - obs1[2 * i];
        float viy = piy - obs1[2 * i + 1];
        float vx = (pjx - obs1[2 * jn])     - vix;
        float vy = (pjy - obs1[2 * jn + 1]) - viy;
        float* dst = out + (size_t)i * 32 + lane * 8;
        #pragma unroll
        for (int e = 0; e < 8; e++) {
            float a = px * Wemb[e]      + py * Wemb[8 + e]
                    + vx * Wemb[16 + e] + vy * Wemb[24 + e]
                    + bemb[e];
            dst[e] = fmaxf(a, 0.0f);
        }
    }
}

// K2: 512 threads = 8 waves, **12-row tiles** -> grid = ceil(n/12) = 512 blocks
// at n=6144 = exactly 2 blocks/CU (balanced; the r14/r15 1.5 blocks/CU imbalance
// doubled K2's wall time). MFMA stays M=16 with rows 12..15 zero-padded and
// store-masked. Wave wv handles unit tiles {wv, wv+8}. LDS 17,920 B.
__global__ __launch_bounds__(512) void lstm_kernel(
    const float* __restrict__ h,   const float* __restrict__ c,
    const u16*  __restrict__ Wgf,  const float* __restrict__ bih,
    const float* __restrict__ bhh,
    const u16*  __restrict__ Wpf,  const float* __restrict__ bp,
    int n, float* __restrict__ out)
{
    __shared__ __align__(16) char lds[17920];
    u16* sXb = (u16*)lds;                     // [16][296] bf16 X=[emb|h], rows 12-15 zero
    u16* sHb = (u16*)(lds + 9472);            // [16][264] bf16 h_new, rows 12-15 zero

    const int t    = threadIdx.x;             // 0..511
    const int i0   = blockIdx.x * 12;         // 12 rows per block
    const int lane = t & 63;
    const int wv   = t >> 6;                  // wave 0..7
    const int fm   = lane & 15;
    const int fq   = lane >> 4;

    // stage emb (fp32 in out) -> sXb[:,0:32): 16x32 entries, one per thread
    {
        int r = t >> 5, e = t & 31;           // r 0..15
        int row = i0 + r;
        float v = (r < 12 && row < n) ? out[(size_t)row * 32 + e] : 0.0f;
        sXb[r * 296 + e] = f2bf(v);
    }
    // stage h -> sXb[:,32:288): 16 rows x 64 float4, 2 per thread
    #pragma unroll
    for (int f = t; f < 16 * 64; f += 512) {
        int r = f >> 6, k4 = f & 63;
        int row = i0 + r;
        float4 hv = (r < 12 && row < n) ? ((const float4*)h)[(size_t)row * 64 + k4]
                                        : make_float4(0.f, 0.f, 0.f, 0.f);
        u16* d = &sXb[r * 296 + 32 + k4 * 4];
        d[0] = f2bf(hv.x); d[1] = f2bf(hv.y); d[2] = f2bf(hv.z); d[3] = f2bf(hv.w);
    }
    __syncthreads();

    // A-frags: lane holds X[row=fm][kt*32 + fq*8 + j]
    bf16x8 afr[9];
    #pragma unroll
    for (int kt = 0; kt < 9; kt++)
        afr[kt] = *(const bf16x8*)&sXb[fm * 296 + kt * 32 + fq * 8];

    // gates + pointwise, unit tiles {wv, wv+8}
    #pragma unroll
    for (int ut2 = 0; ut2 < 2; ut2++) {
        const int ut = wv + ut2 * 8;          // unit tile 0..15
        const int u  = ut * 16 + fm;          // hidden unit this lane owns

        f32x4 acc[4];
        #pragma unroll
        for (int jg = 0; jg < 4; jg++) acc[jg] = (f32x4){0.f, 0.f, 0.f, 0.f};

        #pragma unroll
        for (int jg = 0; jg < 4; jg++) {      // gate type i,f,g,o
            const int gt = jg * 16 + ut;
            const u16* wbase = Wgf + ((size_t)gt * 9) * 512 + lane * 8;
            #pragma unroll
            for (int kt = 0; kt < 9; kt++) {
                bf16x8 bfr = *(const bf16x8*)(wbase + kt * 512);  // coalesced 1 KB
                acc[jg] = __builtin_amdgcn_mfma_f32_16x16x32_bf16(afr[kt], bfr, acc[jg], 0, 0, 0);
            }
        }

        float b0 = bih[u]       + bhh[u];
        float b1 = bih[u + 256] + bhh[u + 256];
        float b2 = bih[u + 512] + bhh[u + 512];
        float b3 = bih[u + 768] + bhh[u + 768];

        #pragma unroll
        for (int r_ = 0; r_ < 4; r_++) {      // D-layout: local row = fq*4 + r_
            int rl = fq * 4 + r_;
            int row = i0 + rl;
            bool valid = (rl < 12) && (row < n);
            float cin = valid ? c[(size_t)row * 256 + u] : 0.0f;
            float gi = acc[0][r_] + b0;
            float gf = acc[1][r_] + b1;
            float gg = acc[2][r_] + b2;
            float go = acc[3][r_] + b3;
            float cn = sigf(gf) * cin + sigf(gi) * tanhf_(gg);
            float hn = sigf(go) * tanhf_(cn);
            sHb[rl * 264 + u] = valid ? f2bf(hn) : (u16)0;
        }
    }
    __syncthreads();

    // pool GEMM: M=16 x N=32 x K=256; waves 0,1 take one n-tile each
    if (wv < 2) {
        bf16x8 ah[8];
        #pragma unroll
        for (int kt = 0; kt < 8; kt++)
            ah[kt] = *(const bf16x8*)&sHb[fm * 264 + kt * 32 + fq * 8];
        const u16* wbase = Wpf + ((size_t)wv * 8) * 512 + lane * 8;
        f32x4 acc = {0.f, 0.f, 0.f, 0.f};
        #pragma unroll
        for (int kt = 0; kt < 8; kt++) {
            bf16x8 bfr = *(const bf16x8*)(wbase + kt * 512);
            acc = __builtin_amdgcn_mfma_f32_16x16x32_bf16(ah[kt], bfr, acc, 0, 0, 0);
        }
        float bias = bp[wv * 16 + fm];
        #pragma unroll
        for (int r_ = 0; r_ < 4; r_++) {
            int rl = fq * 4 + r_;
            int row = i0 + rl;
            if (rl < 12 && row < n) out[(size_t)row * 32 + wv * 16 + fm] = acc[r_] + bias;
        }
    }
}

// ---- round-5 fallback (no workspace) ----
__global__ __launch_bounds__(256) void nnlstm_fallback(
    const float* __restrict__ obs1, const float* __restrict__ obs2,
    const float* __restrict__ h,    const float* __restrict__ c,
    const float* __restrict__ Wemb, const float* __restrict__ bemb,
    const float* __restrict__ Wih,  const float* __restrict__ bih,
    const float* __restrict__ Whh,  const float* __restrict__ bhh,
    const float* __restrict__ Wp,   const float* __restrict__ bp,
    int n, float* __restrict__ out)
{
    __shared__ float sMd[16][64];
    __shared__ int   sMj[16][64];
    __shared__ float sX[16][292];
    __shared__ float sH[16][264];

    const int t   = threadIdx.x;
    const int sub = t & 15;
    const int ii  = t >> 4;
    const int i0  = blockIdx.x * 16;
    const int i   = i0 + ii;

    for (int v = t; v < 16 * 256; v += 256) {
        int r = v >> 8, k = v & 255;
        int row = i0 + r;
        sX[r][32 + k] = (row < n) ? h[(size_t)row * 256 + k] : 0.0f;
    }

    float bd0 = 1e30f, bd1 = 1e30f, bd2 = 1e30f, bd3 = 1e30f;
    int   bj0 = 0x7fffffff, bj1 = 0x7fffffff, bj2 = 0x7fffffff, bj3 = 0x7fffffff;

    if (i < n) {
        const float pix = obs2[2 * i];
        const float piy = obs2[2 * i + 1];
        for (int j = sub; j < n; j += 16) {
            float dx = obs2[2 * j]     - pix;
            float dy = obs2[2 * j + 1] - piy;
            float d2 = __fadd_rn(__fmul_rn(dx, dx), __fmul_rn(dy, dy));
            float dist = __fsqrt_rn(d2);
            if (j == i) continue;
            INS4(dist, j);
        }
    }
    sMd[ii][sub * 4 + 0] = bd0;  sMj[ii][sub * 4 + 0] = bj0;
    sMd[ii][sub * 4 + 1] = bd1;  sMj[ii][sub * 4 + 1] = bj1;
    sMd[ii][sub * 4 + 2] = bd2;  sMj[ii][sub * 4 + 2] = bj2;
    sMd[ii][sub * 4 + 3] = bd3;  sMj[ii][sub * 4 + 3] = bj3;
    __syncthreads();

    if (t < 16) {
        const int r = t;
        const int irow = i0 + r;
        float bd0 = 1e30f, bd1 = 1e30f, bd2 = 1e30f, bd3 = 1e30f;
        int   bj0 = 0x7fffffff, bj1 = 0x7fffffff, bj2 = 0x7fffffff, bj3 = 0x7fffffff;
        for (int q = 0; q < 64; q++) { INS4(sMd[r][q], sMj[r][q]); }

        if (irow < n) {
            float pix = obs2[2 * irow], piy = obs2[2 * irow + 1];
            float vix = pix - obs1[2 * irow];
            float viy = piy - obs1[2 * irow + 1];
            #pragma unroll
            for (int q2 = 0; q2 < 4; q2++) {
                int jn = (q2 == 0) ? bj0 : (q2 == 1) ? bj1 : (q2 == 2) ? bj2 : bj3;
                if (jn < 0 || jn >= n) jn = 0;
                float pjx = obs2[2 * jn], pjy = obs2[2 * jn + 1];
                float px = pjx - pix, py = pjy - piy;
                float vx = (pjx - obs1[2 * jn])     - vix;
                float vy = (pjy - obs1[2 * jn + 1]) - viy;
                #pragma unroll
                for (int e = 0; e < 8; e++) {
                    float a = px * Wemb[e]      + py * Wemb[8 + e]
                            + vx * Wemb[16 + e] + vy * Wemb[24 + e]
                            + bemb[e];
                    sX[r][q2 * 8 + e] = fmaxf(a, 0.0f);
                }
            }
        } else {
            for (int e = 0; e < 32; e++) sX[r][e] = 0.0f;
        }
    }
    __syncthreads();

    const int uu = t;
    float acc[4][16];
    #pragma unroll
    for (int j = 0; j < 4; j++) {
        float b = bih[uu + 256 * j] + bhh[uu + 256 * j];
        #pragma unroll
        for (int r = 0; r < 16; r++) acc[j][r] = b;
    }

    for (int kc = 0; kc < 288; kc++) {
        float w[4];
        #pragma unroll
        for (int j = 0; j < 4; j++) {
            int g = uu + 256 * j;
            w[j] = (kc < 32) ? Wih[(size_t)g * 32 + kc]
                             : Whh[(size_t)g * 256 + (kc - 32)];
        }
        #pragma unroll
        for (int r = 0; r < 16; r++) {
            float x = sX[r][kc];
            #pragma unroll
            for (int j = 0; j < 4; j++) acc[j][r] += w[j] * x;
        }
    }

    for (int r = 0; r < 16; r++) {
        int row = i0 + r;
        float cin = (row < n) ? c[(size_t)row * 256 + uu] : 0.0f;
        float cn = sigf(acc[1][r]) * cin + sigf(acc[0][r]) * tanhf(acc[2][r]);
        float hn = sigf(acc[3][r]) * tanhf(cn);
        sH[r][uu] = hn;
    }
    __syncthreads();

    for (int v = t; v < 16 * 32; v += 256) {
        int r = v >> 5, o = v & 31;
        int row = i0 + r;
        if (row >= n) continue;
        float a = bp[o];
        for (int kc = 0; kc < 256; kc++)
            a += Wp[(size_t)o * 256 + kc] * sH[r][kc];
        out[(size_t)row * 32 + o] = a;
    }
}

extern "C" void kernel_launch(void* const* d_in, const int* in_sizes, int n_in,
                              void* d_out, int out_size, void* d_ws, size_t ws_size,
                              hipStream_t stream) {
    float* out = (float*)d_out;

    int code = 0, n = 0;
    if (n_in != 12) code = 1;
    else {
        n = in_sizes[1] / 2;
        if (n <= 4 || in_sizes[1] != 2 * n)          code = 2;
        else if (in_sizes[0]  != 2 * n)              code = 3;
        else if (in_sizes[2]  != 256 * n)            code = 4;
        else if (in_sizes[3]  != 256 * n)            code = 5;
        else if (in_sizes[4]  != 32 || in_sizes[5] != 8)        code = 6;
        else if (in_sizes[6]  != 32768 || in_sizes[7] != 1024)  code = 7;
        else if (in_sizes[8]  != 262144 || in_sizes[9] != 1024) code = 8;
        else if (in_sizes[10] != 8192 || in_sizes[11] != 32)    code = 9;
        else if (out_size != 32 * n)                 code = 10;
    }
    if (code != 0) {
        diag_kernel<<<1, 1, 0, stream>>>(out, code, out_size);
        return;
    }

    const float* obs1   = (const float*)d_in[0];
    const float* obs2   = (const float*)d_in[1];
    const float* h      = (const float*)d_in[2];
    const float* c      = (const float*)d_in[3];
    const float* W_emb  = (const float*)d_in[4];
    const float* b_emb  = (const float*)d_in[5];
    const float* W_ih   = (const float*)d_in[6];
    const float* b_ih   = (const float*)d_in[7];
    const float* W_hh   = (const float*)d_in[8];
    const float* b_hh   = (const float*)d_in[9];
    const float* W_pool = (const float*)d_in[10];
    const float* b_pool = (const float*)d_in[11];

    const size_t wgf_bytes = (size_t)36864 * 8 * sizeof(u16);   // 589,824
    const size_t wpf_bytes = (size_t)1024 * 8 * sizeof(u16);    //  16,384

    if (ws_size >= wgf_bytes + wpf_bytes && n <= (1 << 24)) {
        u16* Wgf = (u16*)d_ws;
        u16* Wpf = (u16*)((char*)d_ws + wgf_bytes);
        int knn_blocks = (n + 3) / 4;
        knn_prep_kernel<<<knn_blocks + 148, 256, 0, stream>>>(
            obs1, obs2, W_emb, b_emb, W_ih, W_hh, W_pool, Wgf, Wpf,
            n, knn_blocks, out);
        lstm_kernel<<<(n + 11) / 12, 512, 0, stream>>>(
            h, c, Wgf, b_ih, b_hh, Wpf, b_pool, n, out);
    } else {
        nnlstm_fallback<<<(n + 15) / 16, 256, 0, stream>>>(
            obs1, obs2, h, c, W_emb, b_emb, W_ih, b_ih, W_hh, b_hh,
            W_pool, b_pool, n, out);
    }
}